// Round 1
// baseline (71.771 us; speedup 1.0000x reference)
//
#include <hip/hip_runtime.h>

#define SP 56
#define CH 64
#define XSTRIDE 3136   // 56*56 = per-j stride in x, per-i stride in out

// ---------------------------------------------------------------------------
// Prep: build combined coefficient tables from W (64,3,2,64) = W[i][kt][l][j].
// For o>=1 the reference collapses to a 4-tap vertical correlation:
//   b=o-2: C0=W[i,0,1,j]; b=o-1: C1=W[i,0,0,j]+W[i,1,1,j];
//   b=o  : C2=W[i,1,0,j]+W[i,2,1,j]; b=o+1: C3=W[i,2,0,j]   (b clipped to [0,56))
// o==0 wraps (o-1 -> 55): taps b={0,1,54,55} with D={W[i,1,0],W[i,2,0],W[i,0,1],W[i,1,1]}
// Layout: Cv[j*64+i] = float4(C0..C3); Dv at float4 offset 4096.
// ---------------------------------------------------------------------------
__global__ void tsc_prep(const float* __restrict__ W, float4* __restrict__ Cv) {
  int t = blockIdx.x * blockDim.x + threadIdx.x;
  if (t >= CH * CH) return;
  int i = t & 63;
  int j = t >> 6;
  const float* Wi = W + i * 384 + j;   // W[i][kt][l][j]: kt stride 128, l stride 64
  float w00 = Wi[0];                   // kt=0,l=0
  float w01 = Wi[64];                  // kt=0,l=1
  float w10 = Wi[128];                 // kt=1,l=0
  float w11 = Wi[192];                 // kt=1,l=1
  float w20 = Wi[256];                 // kt=2,l=0
  float w21 = Wi[320];                 // kt=2,l=1
  Cv[j * 64 + i]        = make_float4(w01, w00 + w11, w10 + w21, w20);
  Cv[4096 + j * 64 + i] = make_float4(w10, w20, w01, w11);
}

// ---------------------------------------------------------------------------
// Main: block = (o-group of 4, n), 64 threads = 1 wave, lane = output chan i.
// x-window addresses depend only on blockIdx+j -> wave-uniform -> s_load path.
// Coefficient loads are one coalesced dwordx4 per lane per j.
// out[i,o,n] = sum_j sum_{d=0..3} C_d[j][i] * x[j, (n-1)%56, o-2+d]  (clipped),
// with o==0 replaced by the D-tap form.
// ---------------------------------------------------------------------------
__global__ __launch_bounds__(64) void tsc_main(const float* __restrict__ x,
                                               const float4* __restrict__ Cv,
                                               float* __restrict__ out) {
  const int i  = threadIdx.x;     // output channel (lane)
  const int og = blockIdx.x;      // 0..13, group of 4 output rows o
  const int n  = blockIdx.y;      // 0..55, output column
  const int o0 = og * 4;
  const int ns = (n + SP - 1) % SP;          // (n-1) mod 56
  const float* xb = x + ns * SP;             // x[j][ns][b] = xb[j*3136 + b]
  const float4* cb = Cv + i;                 // Cv[j*64 + i]

  float acc0 = 0.f, acc1 = 0.f, acc2 = 0.f, acc3 = 0.f;

  if (og >= 1 && og <= 12) {
    // fully interior: window b = o0-2 .. o0+4 all within [0,56)
    const float* xw = xb + (o0 - 2);
#pragma unroll 4
    for (int j = 0; j < CH; ++j) {
      const float4 c = cb[j * 64];
      const float* xj = xw + j * XSTRIDE;
      float w0 = xj[0], w1 = xj[1], w2 = xj[2], w3 = xj[3];
      float w4 = xj[4], w5 = xj[5], w6 = xj[6];
      acc0 += c.x * w0 + c.y * w1 + c.z * w2 + c.w * w3;
      acc1 += c.x * w1 + c.y * w2 + c.z * w3 + c.w * w4;
      acc2 += c.x * w2 + c.y * w3 + c.z * w4 + c.w * w5;
      acc3 += c.x * w3 + c.y * w4 + c.z * w5 + c.w * w6;
    }
  } else if (og == 13) {
    // o = 52..55; window b = 50..56, b=56 is zero-pad
    const float* xw = xb + 50;
#pragma unroll 4
    for (int j = 0; j < CH; ++j) {
      const float4 c = cb[j * 64];
      const float* xj = xw + j * XSTRIDE;
      float w0 = xj[0], w1 = xj[1], w2 = xj[2];
      float w3 = xj[3], w4 = xj[4], w5 = xj[5];
      acc0 += c.x * w0 + c.y * w1 + c.z * w2 + c.w * w3;
      acc1 += c.x * w1 + c.y * w2 + c.z * w3 + c.w * w4;
      acc2 += c.x * w2 + c.y * w3 + c.z * w4 + c.w * w5;
      acc3 += c.x * w3 + c.y * w4 + c.z * w5;            // b=56 term dropped
    }
  } else {
    // og == 0: o = 0..3; window b = -2..4 (b<0 zero-pad); o==0 uses D taps
    float accD = 0.f;
#pragma unroll 4
    for (int j = 0; j < CH; ++j) {
      const float4 c = cb[j * 64];
      const float4 d = cb[4096 + j * 64];
      const float* xj = xb + j * XSTRIDE;
      float w2 = xj[0], w3 = xj[1], w4 = xj[2], w5 = xj[3], w6 = xj[4];
      // o=1 (s=1): b=-1 masked
      acc1 += c.y * w2 + c.z * w3 + c.w * w4;
      acc2 += c.x * w2 + c.y * w3 + c.z * w4 + c.w * w5;
      acc3 += c.x * w3 + c.y * w4 + c.z * w5 + c.w * w6;
      // o=0: taps b = 0, 1, 54, 55 with D weights
      accD += d.x * xj[0] + d.y * xj[1] + d.z * xj[54] + d.w * xj[55];
    }
    acc0 = accD;
  }

  float* ob = out + i * XSTRIDE + o0 * SP + n;
  ob[0]       = acc0;
  ob[SP]      = acc1;
  ob[2 * SP]  = acc2;
  ob[3 * SP]  = acc3;
}

extern "C" void kernel_launch(void* const* d_in, const int* in_sizes, int n_in,
                              void* d_out, int out_size, void* d_ws, size_t ws_size,
                              hipStream_t stream) {
  const float* x = (const float*)d_in[0];
  const float* W = (const float*)d_in[1];
  float* out = (float*)d_out;
  float4* Cv = (float4*)d_ws;   // needs 8192 float4 = 128 KB

  tsc_prep<<<dim3(16), dim3(256), 0, stream>>>(W, Cv);
  tsc_main<<<dim3(14, 56), dim3(64), 0, stream>>>(x, Cv, out);
}

// Round 2
// 64.831 us; speedup vs baseline: 1.1070x; 1.1070x over previous
//
#include <hip/hip_runtime.h>

#define SP 56
#define CH 64
#define XSTRIDE 3136   // 56*56 = per-j stride in x, per-i stride in out

// ---------------------------------------------------------------------------
// Prep: build combined coefficient tables from W (64,3,2,64) = W[i][kt][l][j].
// For o>=1 the reference collapses to a 4-tap vertical correlation:
//   b=o-2: C0=W[i,0,1,j]; b=o-1: C1=W[i,0,0,j]+W[i,1,1,j];
//   b=o  : C2=W[i,1,0,j]+W[i,2,1,j]; b=o+1: C3=W[i,2,0,j]
// o==0 wraps (o-1 -> 55): taps rows {0,1,54,55} with
//   D = {W[i,1,0,j], W[i,2,0,j], W[i,0,1,j], W[i,1,1,j]}
// Layout: Cv[j*64+i] = float4(C0..C3); D table at float4 offset 4096.
// ---------------------------------------------------------------------------
__global__ void tsc_prep(const float* __restrict__ W, float4* __restrict__ Cv) {
  int t = blockIdx.x * blockDim.x + threadIdx.x;
  if (t >= CH * CH) return;
  int i = t & 63;
  int j = t >> 6;
  const float* Wi = W + i * 384 + j;   // W[i][kt][l][j]: kt stride 128, l stride 64
  float w00 = Wi[0];
  float w01 = Wi[64];
  float w10 = Wi[128];
  float w11 = Wi[192];
  float w20 = Wi[256];
  float w21 = Wi[320];
  Cv[j * 64 + i]        = make_float4(w01, w00 + w11, w10 + w21, w20);
  Cv[4096 + j * 64 + i] = make_float4(w10, w20, w01, w11);
}

// ---------------------------------------------------------------------------
// Main: block = (og 0..13, n 0..55), 256 threads = 4 waves.
// Stage x-window (64 j x 8 rows, circular-bottom / zero-top) into LDS with
// 512 parallel coalesced loads; wave w computes j in [16w,16w+16) for all
// 64 output channels (lane = i); cross-wave reduction in LDS; scatter store.
// ---------------------------------------------------------------------------
__global__ __launch_bounds__(256) void tsc_main(const float* __restrict__ x,
                                                const float4* __restrict__ Cv,
                                                float* __restrict__ out) {
  __shared__ float xs[CH][8];       // 2 KB: xs[j][b], row g = o0-2+b (wrapped/masked)
  __shared__ float red[4][4][64];   // 4 KB: red[wave][s][i]

  const int t  = threadIdx.x;
  const int i  = t & 63;            // output channel (lane)
  const int w  = t >> 6;            // wave id 0..3
  const int og = blockIdx.x;        // 0..13
  const int n  = blockIdx.y;        // 0..55
  const int o0 = og * 4;
  const int ns = (n + SP - 1) % SP; // (n-1) mod 56

  // ---- stage x window into LDS (2 loads per thread, coalesced in b) ----
  const float* xrow = x + ns * SP;
#pragma unroll
  for (int u = t; u < CH * 8; u += 256) {
    int j = u >> 3;
    int b = u & 7;
    int g = o0 - 2 + b;
    if (g < 0) g += SP;                       // circular bottom (only og==0)
    float v = (g < SP) ? xrow[j * XSTRIDE + g] : 0.f;  // zero-pad top
    xs[j][b] = v;
  }
  __syncthreads();

  // ---- per-wave partial sums over 16 j values ----
  float a0 = 0.f, a1 = 0.f, a2 = 0.f, a3 = 0.f;
  const float4* cb = Cv + i;
  const int j0 = w * 16;

  if (og != 0) {
#pragma unroll 4
    for (int jj = 0; jj < 16; ++jj) {
      int j = j0 + jj;
      float4 c = cb[j * 64];
      float x0 = xs[j][0], x1 = xs[j][1], x2 = xs[j][2], x3 = xs[j][3];
      float x4 = xs[j][4], x5 = xs[j][5], x6 = xs[j][6];
      a0 += c.x * x0 + c.y * x1 + c.z * x2 + c.w * x3;
      a1 += c.x * x1 + c.y * x2 + c.z * x3 + c.w * x4;
      a2 += c.x * x2 + c.y * x3 + c.z * x4 + c.w * x5;
      a3 += c.x * x3 + c.y * x4 + c.z * x5 + c.w * x6;
    }
  } else {
    // xs[0]=row54, xs[1]=row55 (wrapped), xs[2..6]=rows 0..4
#pragma unroll 4
    for (int jj = 0; jj < 16; ++jj) {
      int j = j0 + jj;
      float4 c = cb[j * 64];
      float4 d = cb[4096 + j * 64];
      float x0 = xs[j][0], x1 = xs[j][1], x2 = xs[j][2], x3 = xs[j][3];
      float x4 = xs[j][4], x5 = xs[j][5], x6 = xs[j][6];
      a0 += d.x * x2 + d.y * x3 + d.z * x0 + d.w * x1;   // o=0: D taps
      a1 += c.y * x2 + c.z * x3 + c.w * x4;              // o=1: g=-1 tap dropped
      a2 += c.x * x2 + c.y * x3 + c.z * x4 + c.w * x5;
      a3 += c.x * x3 + c.y * x4 + c.z * x5 + c.w * x6;
    }
  }

  red[w][0][i] = a0;
  red[w][1][i] = a1;
  red[w][2][i] = a2;
  red[w][3][i] = a3;
  __syncthreads();

  // ---- cross-wave reduction + store: thread t -> (s = t>>6, i = t&63) ----
  {
    int s  = t >> 6;
    int ii = t & 63;
    float v = red[0][s][ii] + red[1][s][ii] + red[2][s][ii] + red[3][s][ii];
    out[ii * XSTRIDE + (o0 + s) * SP + n] = v;
  }
}

extern "C" void kernel_launch(void* const* d_in, const int* in_sizes, int n_in,
                              void* d_out, int out_size, void* d_ws, size_t ws_size,
                              hipStream_t stream) {
  const float* x = (const float*)d_in[0];
  const float* W = (const float*)d_in[1];
  float* out = (float*)d_out;
  float4* Cv = (float4*)d_ws;   // 8192 float4 = 128 KB scratch

  tsc_prep<<<dim3(16), dim3(256), 0, stream>>>(W, Cv);
  tsc_main<<<dim3(14, 56), dim3(256), 0, stream>>>(x, Cv, out);
}